// Round 5
// baseline (217.260 us; speedup 1.0000x reference)
//
#include <hip/hip_runtime.h>
#include <cstdint>

#define P 7
#define PP 49
#define IMG 64
#define PIX 4096
#define PAD 3
#define XS 70     // padded tile dim
#define XSTR 71   // padded tile row stride (bank-conflict pad)

// ---- 10-wide row load into named scalars (no arrays -> no scratch risk) ----
#define LOADROW(BP) \
    r0=(BP)[0]; r1=(BP)[1]; r2=(BP)[2]; r3=(BP)[3]; r4=(BP)[4]; \
    r5=(BP)[5]; r6=(BP)[6]; r7=(BP)[7]; r8=(BP)[8]; r9=(BP)[9];

// per-row sum step: each pixel p accumulates its 7 values in ascending j
#define SUM4 \
    s0+=r0; s1+=r1; s2+=r2; s3+=r3; \
    s0+=r1; s1+=r2; s2+=r3; s3+=r4; \
    s0+=r2; s1+=r3; s2+=r4; s3+=r5; \
    s0+=r3; s1+=r4; s2+=r5; s3+=r6; \
    s0+=r4; s1+=r5; s2+=r6; s3+=r7; \
    s0+=r5; s1+=r6; s2+=r7; s3+=r8; \
    s0+=r6; s1+=r7; s2+=r8; s3+=r9;

#define S1J(I,J,RA,RB,RC,RD) { \
    const float w = W1[((I)*7+(J))*8 + l]; \
    a0 = fmaf(w, (RA)-mu0, a0); a1 = fmaf(w, (RB)-mu1, a1); \
    a2 = fmaf(w, (RC)-mu2, a2); a3 = fmaf(w, (RD)-mu3, a3); }

#define S1ROW(I) \
    LOADROW(base1 + (I)*XSTR) \
    S1J(I,0,r0,r1,r2,r3) S1J(I,1,r1,r2,r3,r4) S1J(I,2,r2,r3,r4,r5) \
    S1J(I,3,r3,r4,r5,r6) S1J(I,4,r4,r5,r6,r7) S1J(I,5,r5,r6,r7,r8) \
    S1J(I,6,r6,r7,r8,r9)

#define S2J(I,J,RA,RB,RC,RD) { \
    const float t0=(RA)-mu0, t1=(RB)-mu1, t2=(RC)-mu2, t3=(RD)-mu3; \
    const float* wp = W2 + ((I)*7+(J))*8; \
    float w; \
    w=wp[0]; a00=fmaf(w,t0,a00); a01=fmaf(w,t1,a01); a02=fmaf(w,t2,a02); a03=fmaf(w,t3,a03); \
    w=wp[1]; a10=fmaf(w,t0,a10); a11=fmaf(w,t1,a11); a12=fmaf(w,t2,a12); a13=fmaf(w,t3,a13); \
    w=wp[2]; a20=fmaf(w,t0,a20); a21=fmaf(w,t1,a21); a22=fmaf(w,t2,a22); a23=fmaf(w,t3,a23); \
    w=wp[3]; a30=fmaf(w,t0,a30); a31=fmaf(w,t1,a31); a32=fmaf(w,t2,a32); a33=fmaf(w,t3,a33); \
    w=wp[4]; a40=fmaf(w,t0,a40); a41=fmaf(w,t1,a41); a42=fmaf(w,t2,a42); a43=fmaf(w,t3,a43); \
    w=wp[5]; a50=fmaf(w,t0,a50); a51=fmaf(w,t1,a51); a52=fmaf(w,t2,a52); a53=fmaf(w,t3,a53); \
    w=wp[6]; a60=fmaf(w,t0,a60); a61=fmaf(w,t1,a61); a62=fmaf(w,t2,a62); a63=fmaf(w,t3,a63); \
    w=wp[7]; a70=fmaf(w,t0,a70); a71=fmaf(w,t1,a71); a72=fmaf(w,t2,a72); a73=fmaf(w,t3,a73); }

#define S2ROW(I) \
    LOADROW(base2 + (I)*XSTR) \
    S2J(I,0,r0,r1,r2,r3) S2J(I,1,r1,r2,r3,r4) S2J(I,2,r2,r3,r4,r5) \
    S2J(I,3,r3,r4,r5,r6) S2J(I,4,r4,r5,r6,r7) S2J(I,5,r5,r6,r7,r8) \
    S2J(I,6,r6,r7,r8,r9)

// ---------------------------------------------------------------------------
// One block per output channel ch = l*64 + img (512 blocks, 1024 threads).
// Each thread owns a strip of 4 consecutive pixels in one row: the 4 windows
// share a 7x10 footprint -> 70 LDS reads per strip (17.5/px) instead of
// 49/px, loaded twice (sum pass, fma pass) into named scalars. Per-pixel op
// order (row-major window sum; sub-then-fma chain, k ascending) is
// bit-identical to the verified rounds. Weights via uniform scalar loads.
// ---------------------------------------------------------------------------
__global__ __launch_bounds__(1024, 4) void stage_kernel(
    const float* __restrict__ x,    // [64][64][64]
    const float* __restrict__ W1,   // [49][8]
    const float* __restrict__ W2,   // [49][8]
    uint8_t* __restrict__ codes)    // [512][4096]
{
    __shared__ float xs[XS * XSTR];
    __shared__ float ms[XS * XSTR];

    const int ch  = blockIdx.x;
    const int l   = ch >> 6;
    const int img = ch & 63;
    const int tid = threadIdx.x;

    // zero ms (stage-2 SAME padding) and load x zero-padded by 3
    #pragma unroll 1
    for (int i = tid; i < XS * XSTR; i += 1024) ms[i] = 0.f;
    const float* xb = x + (size_t)img * PIX;
    #pragma unroll 1
    for (int idx = tid; idx < XS * XSTR; idx += 1024) {
        int r  = idx / XSTR, cc = idx - r * XSTR;
        int xr = r - PAD,    xc = cc - PAD;
        float v = 0.f;
        if (xr >= 0 && xr < IMG && xc >= 0 && xc < IMG)
            v = xb[xr * IMG + xc];
        xs[idx] = v;
    }
    __syncthreads();

    // ---- stage 1: 64x64 interior, one 4-px strip per thread ----
    {
        const int r  = tid >> 4;          // 0..63
        const int cs = (tid & 15) * 4;    // 0..60
        const float* base1 = &xs[r * XSTR + cs];
        float r0,r1,r2,r3,r4,r5,r6,r7,r8,r9;
        float s0=0.f, s1=0.f, s2=0.f, s3=0.f;
        LOADROW(base1 + 0*XSTR) SUM4
        LOADROW(base1 + 1*XSTR) SUM4
        LOADROW(base1 + 2*XSTR) SUM4
        LOADROW(base1 + 3*XSTR) SUM4
        LOADROW(base1 + 4*XSTR) SUM4
        LOADROW(base1 + 5*XSTR) SUM4
        LOADROW(base1 + 6*XSTR) SUM4
        const float mu0 = s0 / 49.0f, mu1 = s1 / 49.0f;
        const float mu2 = s2 / 49.0f, mu3 = s3 / 49.0f;
        float a0=0.f, a1=0.f, a2=0.f, a3=0.f;
        S1ROW(0) S1ROW(1) S1ROW(2) S1ROW(3) S1ROW(4) S1ROW(5) S1ROW(6)
        float* mp = &ms[(r + PAD) * XSTR + (cs + PAD)];
        mp[0] = a0; mp[1] = a1; mp[2] = a2; mp[3] = a3;
    }
    __syncthreads();

    // ---- stage 2 + code bits: one 4-px strip per thread ----
    {
        const int pr = tid >> 4;          // 0..63
        const int pc = (tid & 15) * 4;    // 0..60
        const float* base2 = &ms[pr * XSTR + pc];
        float r0,r1,r2,r3,r4,r5,r6,r7,r8,r9;
        float s0=0.f, s1=0.f, s2=0.f, s3=0.f;
        LOADROW(base2 + 0*XSTR) SUM4
        LOADROW(base2 + 1*XSTR) SUM4
        LOADROW(base2 + 2*XSTR) SUM4
        LOADROW(base2 + 3*XSTR) SUM4
        LOADROW(base2 + 4*XSTR) SUM4
        LOADROW(base2 + 5*XSTR) SUM4
        LOADROW(base2 + 6*XSTR) SUM4
        const float mu0 = s0 / 49.0f, mu1 = s1 / 49.0f;
        const float mu2 = s2 / 49.0f, mu3 = s3 / 49.0f;
        float a00=0.f,a01=0.f,a02=0.f,a03=0.f, a10=0.f,a11=0.f,a12=0.f,a13=0.f;
        float a20=0.f,a21=0.f,a22=0.f,a23=0.f, a30=0.f,a31=0.f,a32=0.f,a33=0.f;
        float a40=0.f,a41=0.f,a42=0.f,a43=0.f, a50=0.f,a51=0.f,a52=0.f,a53=0.f;
        float a60=0.f,a61=0.f,a62=0.f,a63=0.f, a70=0.f,a71=0.f,a72=0.f,a73=0.f;
        S2ROW(0) S2ROW(1) S2ROW(2) S2ROW(3) S2ROW(4) S2ROW(5) S2ROW(6)
        uint32_t c0 = 0, c1 = 0, c2 = 0, c3 = 0;
        c0 |= (a00>0.f)?128u:0u; c1 |= (a01>0.f)?128u:0u; c2 |= (a02>0.f)?128u:0u; c3 |= (a03>0.f)?128u:0u;
        c0 |= (a10>0.f)? 64u:0u; c1 |= (a11>0.f)? 64u:0u; c2 |= (a12>0.f)? 64u:0u; c3 |= (a13>0.f)? 64u:0u;
        c0 |= (a20>0.f)? 32u:0u; c1 |= (a21>0.f)? 32u:0u; c2 |= (a22>0.f)? 32u:0u; c3 |= (a23>0.f)? 32u:0u;
        c0 |= (a30>0.f)? 16u:0u; c1 |= (a31>0.f)? 16u:0u; c2 |= (a32>0.f)? 16u:0u; c3 |= (a33>0.f)? 16u:0u;
        c0 |= (a40>0.f)?  8u:0u; c1 |= (a41>0.f)?  8u:0u; c2 |= (a42>0.f)?  8u:0u; c3 |= (a43>0.f)?  8u:0u;
        c0 |= (a50>0.f)?  4u:0u; c1 |= (a51>0.f)?  4u:0u; c2 |= (a52>0.f)?  4u:0u; c3 |= (a53>0.f)?  4u:0u;
        c0 |= (a60>0.f)?  2u:0u; c1 |= (a61>0.f)?  2u:0u; c2 |= (a62>0.f)?  2u:0u; c3 |= (a63>0.f)?  2u:0u;
        c0 |= (a70>0.f)?  1u:0u; c1 |= (a71>0.f)?  1u:0u; c2 |= (a72>0.f)?  1u:0u; c3 |= (a73>0.f)?  1u:0u;
        uint32_t packed = c0 | (c1 << 8) | (c2 << 16) | (c3 << 24);
        *(uint32_t*)(codes + (size_t)ch * PIX + 4 * tid) = packed;
    }
}

// ---------------------------------------------------------------------------
// Kernel B: histogram + entropy (unchanged -- not the bottleneck)
// ---------------------------------------------------------------------------
#define CPB 32

__global__ __launch_bounds__(256) void hist_kernel(
    const uint8_t* __restrict__ codes,  // [512][4096]
    float* __restrict__ out)            // [49*256][512]
{
    __shared__ uint32_t hist[256 * 33];

    const int bid   = blockIdx.x;       // 0..783
    const int cgrp  = bid & 15;
    const int nb    = bid >> 4;         // 0..48
    const int bi    = nb / 7, bj = nb - bi * 7;
    const int tid   = threadIdx.x;
    const int cbase = cgrp * CPB;

    for (int i = tid; i < 256 * 33; i += 256) hist[i] = 0;
    __syncthreads();

    const int cl  = tid >> 3;           // 0..31
    const int sub = tid & 7;            // 0..7
    const uint8_t* cp = codes + (size_t)(cbase + cl) * PIX;
    #pragma unroll
    for (int rr = 0; rr < 2; ++rr) {
        int row = bi * 8 + (sub * 2 + rr);
        const uint8_t* rp = cp + row * 64 + bj * 8;
        uint64_t v0 = *(const uint64_t*)(rp);
        uint64_t v1 = *(const uint64_t*)(rp + 8);
        #pragma unroll
        for (int t = 0; t < 8; ++t)
            atomicAdd(&hist[(uint32_t)((v0 >> (8 * t)) & 255u) * 33 + cl], 1u);
        #pragma unroll
        for (int t = 0; t < 8; ++t)
            atomicAdd(&hist[(uint32_t)((v1 >> (8 * t)) & 255u) * 33 + cl], 1u);
    }
    __syncthreads();

    const int lane_c = tid & 31;
    const int bin0   = tid >> 5;        // 0..7
    for (int i = 0; i < 32; ++i) {
        int bin = i * 8 + bin0;
        uint32_t cnt = hist[bin * 33 + lane_c];
        float ent = 0.f;
        if (cnt > 0) {
            float pz = (float)cnt * (1.0f / 256.0f);
            ent = -pz * log2f(pz);
        }
        out[((size_t)(nb * 256 + bin)) * 512 + cbase + lane_c] = ent;
    }
}

extern "C" void kernel_launch(void* const* d_in, const int* in_sizes, int n_in,
                              void* d_out, int out_size, void* d_ws, size_t ws_size,
                              hipStream_t stream) {
    const float* x  = (const float*)d_in[0];
    const float* W1 = (const float*)d_in[1];
    const float* W2 = (const float*)d_in[2];
    float* out = (float*)d_out;
    uint8_t* codes = (uint8_t*)d_ws;   // 512*4096 = 2 MB

    stage_kernel<<<512, 1024, 0, stream>>>(x, W1, W2, codes);
    hist_kernel<<<784, 256, 0, stream>>>(codes, out);
}

// Round 6
// 125.479 us; speedup vs baseline: 1.7315x; 1.7315x over previous
//
#include <hip/hip_runtime.h>
#include <cstdint>

#define P 7
#define PP 49
#define IMG 64
#define PIX 4096
#define XSTR 71    // LDS tile row stride (odd -> 2-way bank aliasing, free)
#define XROWS 28   // xs tile rows: x rows q*16-6 .. q*16+21
#define MROWS 22   // ms tile rows: maps1 rows q*16-3 .. q*16+18

// ---- 7x8 window in 56 named scalars (no arrays -> no scratch) ----
#define DECLW \
    float x00,x01,x02,x03,x04,x05,x06,x07; \
    float x10,x11,x12,x13,x14,x15,x16,x17; \
    float x20,x21,x22,x23,x24,x25,x26,x27; \
    float x30,x31,x32,x33,x34,x35,x36,x37; \
    float x40,x41,x42,x43,x44,x45,x46,x47; \
    float x50,x51,x52,x53,x54,x55,x56,x57; \
    float x60,x61,x62,x63,x64,x65,x66,x67;

#define LDROW(i, BP) \
    x##i##0=(BP)[0]; x##i##1=(BP)[1]; x##i##2=(BP)[2]; x##i##3=(BP)[3]; \
    x##i##4=(BP)[4]; x##i##5=(BP)[5]; x##i##6=(BP)[6]; x##i##7=(BP)[7];

#define LDWIN(B) \
    LDROW(0,(B)+0*XSTR) LDROW(1,(B)+1*XSTR) LDROW(2,(B)+2*XSTR) \
    LDROW(3,(B)+3*XSTR) LDROW(4,(B)+4*XSTR) LDROW(5,(B)+5*XSTR) \
    LDROW(6,(B)+6*XSTR)

// per-row window sums: px0 uses cols 0..6, px1 uses 1..7, each k-ascending
#define SUMROW(i) \
    s0+=x##i##0; s1+=x##i##1; s0+=x##i##1; s1+=x##i##2; \
    s0+=x##i##2; s1+=x##i##3; s0+=x##i##3; s1+=x##i##4; \
    s0+=x##i##4; s1+=x##i##5; s0+=x##i##5; s1+=x##i##6; \
    s0+=x##i##6; s1+=x##i##7;

#define SUMALL SUMROW(0) SUMROW(1) SUMROW(2) SUMROW(3) SUMROW(4) SUMROW(5) SUMROW(6)

// ---- stage 1: one filter, 2 px ----
#define S1TAP(i,j,jp) { const float w = W1[((i)*7+(j))*8 + l]; \
    a0 = fmaf(w, x##i##j - mu0, a0); b0 = fmaf(w, x##i##jp - mu1, b0); }
#define S1ROW(i) \
    S1TAP(i,0,1) S1TAP(i,1,2) S1TAP(i,2,3) S1TAP(i,3,4) \
    S1TAP(i,4,5) S1TAP(i,5,6) S1TAP(i,6,7)
#define S1ALL S1ROW(0) S1ROW(1) S1ROW(2) S1ROW(3) S1ROW(4) S1ROW(5) S1ROW(6)

// ---- stage 2: 8 filters, 2 px ----
#define S2TAP(i,j,jp) { \
    const float t0 = x##i##j - mu0, t1 = x##i##jp - mu1; \
    const float* wp = W2 + ((i)*7+(j))*8; float w; \
    w=wp[0]; a0=fmaf(w,t0,a0); b0=fmaf(w,t1,b0); \
    w=wp[1]; a1=fmaf(w,t0,a1); b1=fmaf(w,t1,b1); \
    w=wp[2]; a2=fmaf(w,t0,a2); b2=fmaf(w,t1,b2); \
    w=wp[3]; a3=fmaf(w,t0,a3); b3=fmaf(w,t1,b3); \
    w=wp[4]; a4=fmaf(w,t0,a4); b4=fmaf(w,t1,b4); \
    w=wp[5]; a5=fmaf(w,t0,a5); b5=fmaf(w,t1,b5); \
    w=wp[6]; a6=fmaf(w,t0,a6); b6=fmaf(w,t1,b6); \
    w=wp[7]; a7=fmaf(w,t0,a7); b7=fmaf(w,t1,b7); }
#define S2ROW(i) \
    S2TAP(i,0,1) S2TAP(i,1,2) S2TAP(i,2,3) S2TAP(i,3,4) \
    S2TAP(i,4,5) S2TAP(i,5,6) S2TAP(i,6,7)
#define S2ALL S2ROW(0) S2ROW(1) S2ROW(2) S2ROW(3) S2ROW(4) S2ROW(5) S2ROW(6)

// ---------------------------------------------------------------------------
// One block per (channel, row-quarter): 2048 blocks x 256 threads.
// Each thread processes strips of 2 consecutive pixels; the 7x8 window is
// loaded ONCE into named registers (ds_read2-mergeable), then sum pass and
// fmaf chains run from registers. Per-pixel op order bit-identical to the
// verified rounds. launch_bounds(256,4) -> 128-VGPR cap (live set ~90).
// ---------------------------------------------------------------------------
__global__ __launch_bounds__(256, 4) void stage_kernel(
    const float* __restrict__ x,    // [64][64][64]
    const float* __restrict__ W1,   // [49][8]
    const float* __restrict__ W2,   // [49][8]
    uint8_t* __restrict__ codes)    // [512][4096]
{
    __shared__ float xs[XROWS * XSTR];  // x rows q16-6 .. q16+21, cols -3..67
    __shared__ float ms[MROWS * XSTR];  // maps1 rows q16-3 .. q16+18, cols -3..67

    const int b    = blockIdx.x;
    const int ch   = b >> 2;
    const int q16  = (b & 3) * 16;
    const int l    = ch >> 6;
    const int img  = ch & 63;
    const int tid  = threadIdx.x;

    // zero ms (stage-2 SAME padding: pad cols + out-of-image rows stay 0)
    #pragma unroll 1
    for (int i = tid; i < MROWS * XSTR; i += 256) ms[i] = 0.f;

    // load xs zero-padded
    const float* xb = x + (size_t)img * PIX;
    #pragma unroll 1
    for (int idx = tid; idx < XROWS * XSTR; idx += 256) {
        int r  = idx / XSTR, c = idx - r * XSTR;
        int gr = q16 - 6 + r, gc = c - 3;
        float v = 0.f;
        if (gr >= 0 && gr < IMG && gc >= 0 && gc < IMG)
            v = xb[gr * IMG + gc];
        xs[idx] = v;
    }
    __syncthreads();

    // ---- stage 1: 22 rows x 32 col-strips = 704 strips ----
    #pragma unroll 1
    for (int it = 0; it < 3; ++it) {
        int s = tid + it * 256;
        if (s < MROWS * 32) {
            const int row = s >> 5;           // 0..21
            const int cs2 = (s & 31) * 2;     // 0..62
            const float* bp = &xs[row * XSTR + cs2];
            DECLW
            LDWIN(bp)
            float s0 = 0.f, s1 = 0.f;
            SUMALL
            const float mu0 = s0 / 49.0f, mu1 = s1 / 49.0f;
            float a0 = 0.f, b0 = 0.f;
            S1ALL
            const int gm = q16 - 3 + row;
            const bool in_img = (gm >= 0) && (gm < IMG);
            float* mp = &ms[row * XSTR + 3 + cs2];
            mp[0] = in_img ? a0 : 0.f;
            mp[1] = in_img ? b0 : 0.f;
        }
    }
    __syncthreads();

    // ---- stage 2 + code bits: 16 rows x 32 col-strips = 512 strips ----
    uint8_t* cg = codes + (size_t)ch * PIX;
    #pragma unroll 1
    for (int it = 0; it < 2; ++it) {
        int s = tid + it * 256;
        const int rr  = s >> 5;               // 0..15
        const int cs2 = (s & 31) * 2;         // 0..62
        const float* bp = &ms[rr * XSTR + cs2];
        DECLW
        LDWIN(bp)
        float s0 = 0.f, s1 = 0.f;
        SUMALL
        const float mu0 = s0 / 49.0f, mu1 = s1 / 49.0f;
        float a0=0.f,a1=0.f,a2=0.f,a3=0.f,a4=0.f,a5=0.f,a6=0.f,a7=0.f;
        float b0=0.f,b1=0.f,b2=0.f,b3=0.f,b4=0.f,b5=0.f,b6=0.f,b7=0.f;
        S2ALL
        uint32_t c0 = 0, c1 = 0;
        c0 |= (a0>0.f)?128u:0u; c1 |= (b0>0.f)?128u:0u;
        c0 |= (a1>0.f)? 64u:0u; c1 |= (b1>0.f)? 64u:0u;
        c0 |= (a2>0.f)? 32u:0u; c1 |= (b2>0.f)? 32u:0u;
        c0 |= (a3>0.f)? 16u:0u; c1 |= (b3>0.f)? 16u:0u;
        c0 |= (a4>0.f)?  8u:0u; c1 |= (b4>0.f)?  8u:0u;
        c0 |= (a5>0.f)?  4u:0u; c1 |= (b5>0.f)?  4u:0u;
        c0 |= (a6>0.f)?  2u:0u; c1 |= (b6>0.f)?  2u:0u;
        c0 |= (a7>0.f)?  1u:0u; c1 |= (b7>0.f)?  1u:0u;
        *(uint16_t*)(cg + (q16 + rr) * 64 + cs2) = (uint16_t)(c0 | (c1 << 8));
    }
}

// ---------------------------------------------------------------------------
// Kernel B: histogram + entropy (unchanged)
// ---------------------------------------------------------------------------
#define CPB 32

__global__ __launch_bounds__(256) void hist_kernel(
    const uint8_t* __restrict__ codes,  // [512][4096]
    float* __restrict__ out)            // [49*256][512]
{
    __shared__ uint32_t hist[256 * 33];

    const int bid   = blockIdx.x;       // 0..783
    const int cgrp  = bid & 15;
    const int nb    = bid >> 4;         // 0..48
    const int bi    = nb / 7, bj = nb - bi * 7;
    const int tid   = threadIdx.x;
    const int cbase = cgrp * CPB;

    for (int i = tid; i < 256 * 33; i += 256) hist[i] = 0;
    __syncthreads();

    const int cl  = tid >> 3;           // 0..31
    const int sub = tid & 7;            // 0..7
    const uint8_t* cp = codes + (size_t)(cbase + cl) * PIX;
    #pragma unroll
    for (int rr = 0; rr < 2; ++rr) {
        int row = bi * 8 + (sub * 2 + rr);
        const uint8_t* rp = cp + row * 64 + bj * 8;
        uint64_t v0 = *(const uint64_t*)(rp);
        uint64_t v1 = *(const uint64_t*)(rp + 8);
        #pragma unroll
        for (int t = 0; t < 8; ++t)
            atomicAdd(&hist[(uint32_t)((v0 >> (8 * t)) & 255u) * 33 + cl], 1u);
        #pragma unroll
        for (int t = 0; t < 8; ++t)
            atomicAdd(&hist[(uint32_t)((v1 >> (8 * t)) & 255u) * 33 + cl], 1u);
    }
    __syncthreads();

    const int lane_c = tid & 31;
    const int bin0   = tid >> 5;        // 0..7
    for (int i = 0; i < 32; ++i) {
        int bin = i * 8 + bin0;
        uint32_t cnt = hist[bin * 33 + lane_c];
        float ent = 0.f;
        if (cnt > 0) {
            float pz = (float)cnt * (1.0f / 256.0f);
            ent = -pz * log2f(pz);
        }
        out[((size_t)(nb * 256 + bin)) * 512 + cbase + lane_c] = ent;
    }
}

extern "C" void kernel_launch(void* const* d_in, const int* in_sizes, int n_in,
                              void* d_out, int out_size, void* d_ws, size_t ws_size,
                              hipStream_t stream) {
    const float* x  = (const float*)d_in[0];
    const float* W1 = (const float*)d_in[1];
    const float* W2 = (const float*)d_in[2];
    float* out = (float*)d_out;
    uint8_t* codes = (uint8_t*)d_ws;   // 512*4096 = 2 MB

    stage_kernel<<<2048, 256, 0, stream>>>(x, W1, W2, codes);
    hist_kernel<<<784, 256, 0, stream>>>(codes, out);
}